// Round 1
// baseline (129.706 us; speedup 1.0000x reference)
//
#include <hip/hip_runtime.h>

// NeRF fused kernel for MI355X (gfx950).
// B=16384 rays, H=128, NS=64 samples, MLP 3->128->128->4, volume rendering.
// Strategy: f16 MFMA (16x16x32) for layers 2 and 3 (95% of FLOPs), fp32 VALU
// for layer 1 and rendering. f16 (not bf16): threshold 80 on |ref|~4000 needs
// ~0.5% relative; bf16's 8x coarser mantissa would be borderline.

typedef _Float16 f16;
typedef __attribute__((ext_vector_type(8))) _Float16 half8;   // 4 VGPRs: MFMA A/B frag
typedef __attribute__((ext_vector_type(4))) float floatx4;    // MFMA C/D frag

#define H 128
#define NS 64
#define NRAY_PER_BLK 2
#define A_PAD 136   // 128+8 f16: rows stay 16B-aligned (272B=17*16), lane stride
                    // 68 dwords -> bank 4*m%32 -> 2-way conflict (free per m136)

// ---------------------------------------------------------------------------
// Setup kernel: convert W2 (fp32 128x128) and W3 (fp32 128x4, zero-padded to
// 128x16) into f16 B-fragment order for mfma_f32_16x16x32_f16:
//   lane holds B[k][n] with n = lane&15, k = kstep*32 + (lane>>4)*8 + j, j=0..7
// ws layout: frag_idx = (kstep*8 + ntile)*64 + lane; element j at ws[frag*8+j].
// Main kernel then loads frags with perfectly coalesced global dwordx4 (L2-hot).
// ---------------------------------------------------------------------------
__global__ void nerf_setup(const float* __restrict__ W2, const float* __restrict__ W3,
                           f16* __restrict__ wsW2, f16* __restrict__ wsW3) {
  int t = blockIdx.x * blockDim.x + threadIdx.x;
  if (t < 8192) {                       // W2 frags: 4 ksteps * 8 ntiles * 64 lanes * 4 dwords
    int j2 = t & 3, lane = (t >> 2) & 63, nt = (t >> 8) & 7, ks = t >> 11;
    int k = ks * 32 + ((lane >> 4) * 8) + 2 * j2;
    int n = nt * 16 + (lane & 15);
    wsW2[2 * t]     = (f16)W2[k * H + n];
    wsW2[2 * t + 1] = (f16)W2[(k + 1) * H + n];
  } else if (t < 9216) {                // W3 frags: 4 ksteps * 1 ntile * 64 lanes * 4 dwords
    int u = t - 8192;
    int j2 = u & 3, lane = (u >> 2) & 63, ks = u >> 8;
    int k = ks * 32 + ((lane >> 4) * 8) + 2 * j2;
    int c = lane & 15;
    wsW3[2 * u]     = (c < 4) ? (f16)W3[k * 4 + c]       : (f16)0.0f;
    wsW3[2 * u + 1] = (c < 4) ? (f16)W3[(k + 1) * 4 + c] : (f16)0.0f;
  }
}

// ---------------------------------------------------------------------------
// Main kernel: one block = 2 rays = 128 points, 256 threads = 4 waves.
// Each wave owns 32 point-rows for ALL phases -> no __syncthreads needed until
// rendering (which needs 64 rows = 2 waves per ray).
// ---------------------------------------------------------------------------
__global__ __launch_bounds__(256, 2) void nerf_main(
    const float* __restrict__ origins, const float* __restrict__ dirs,
    const float* __restrict__ W1, const float* __restrict__ b1,
    const float* __restrict__ b2, const float* __restrict__ b3,
    const f16* __restrict__ wsW2, const f16* __restrict__ wsW3,
    float* __restrict__ out)
{
  __shared__ __align__(16) f16   a_lds[128][A_PAD];  // h1, then reused for h2
  __shared__ __align__(16) float f_lds[128][4];      // MLP output per point

  const int t    = threadIdx.x;
  const int w    = t >> 6;          // wave 0..3
  const int lane = t & 63;
  const int quad = lane >> 4;
  const int l16  = lane & 15;
  const int prow0 = w * 32;         // this wave's first point-row
  const float delta = (6.0f - 2.0f) / NS;  // near=2, far=6 (fixed by problem)

  // ---- Phase 1: h1 = relu(x @ W1 + b1), fp32 VALU -> f16 LDS ----
  // lane handles cols k0,k0+1 for this wave's 32 rows; per-lane W1 cached in regs.
  {
    const int ray = blockIdx.x * NRAY_PER_BLK + (w >> 1);
    const float o0 = origins[ray*3+0], o1 = origins[ray*3+1], o2 = origins[ray*3+2];
    const float d0 = dirs[ray*3+0],    d1 = dirs[ray*3+1],    d2 = dirs[ray*3+2];
    const int k0 = 2 * lane;
    const float wa0 = W1[0*H+k0],   wa1 = W1[1*H+k0],   wa2 = W1[2*H+k0];
    const float wb0 = W1[0*H+k0+1], wb1 = W1[1*H+k0+1], wb2 = W1[2*H+k0+1];
    const float ba = b1[k0], bb = b1[k0+1];
    const int s0 = (w & 1) * 32;    // sample index offset within the ray
    #pragma unroll 4
    for (int i = 0; i < 32; ++i) {
      const float m  = 2.0f + (s0 + i + 0.5f) * delta;
      const float x0 = fmaf(m, d0, o0), x1 = fmaf(m, d1, o1), x2 = fmaf(m, d2, o2);
      float ha = fmaf(x2, wa2, fmaf(x1, wa1, fmaf(x0, wa0, ba)));
      float hb = fmaf(x2, wb2, fmaf(x1, wb1, fmaf(x0, wb0, bb)));
      ha = fmaxf(ha, 0.0f); hb = fmaxf(hb, 0.0f);
      union { f16 h[2]; unsigned int u; } pk;
      pk.h[0] = (f16)ha; pk.h[1] = (f16)hb;
      *(unsigned int*)&a_lds[prow0 + i][k0] = pk.u;  // b32 write, 2-way banks: free
    }
  }
  // No barrier: this wave reads back only the 32 rows it just wrote.

  // ---- Phase 2: h2 = relu(h1 @ W2 + b2), MFMA 16x16x32 f16 ----
  // All 32 B-frags (4 ksteps x 8 ntiles) live in registers (128 VGPRs), loaded
  // coalesced from ws. Inner loop: 2 ds_read_b128 (A) + 16 MFMA per kstep.
  half8 bw2[4][8];
  #pragma unroll
  for (int ks = 0; ks < 4; ++ks)
    #pragma unroll
    for (int nt = 0; nt < 8; ++nt)
      bw2[ks][nt] = ((const half8*)wsW2)[(ks*8 + nt)*64 + lane];

  floatx4 acc[2][8];
  #pragma unroll
  for (int tr = 0; tr < 2; ++tr)
    #pragma unroll
    for (int nt = 0; nt < 8; ++nt)
      acc[tr][nt] = (floatx4)(0.0f);

  #pragma unroll
  for (int ks = 0; ks < 4; ++ks) {
    // A-frag: lane holds A[m=l16][k = ks*32 + quad*8 + j], contiguous -> b128
    const half8 a0 = *(const half8*)&a_lds[prow0 + l16][ks*32 + quad*8];
    const half8 a1 = *(const half8*)&a_lds[prow0 + 16 + l16][ks*32 + quad*8];
    #pragma unroll
    for (int nt = 0; nt < 8; ++nt) {
      acc[0][nt] = __builtin_amdgcn_mfma_f32_16x16x32_f16(a0, bw2[ks][nt], acc[0][nt], 0, 0, 0);
      acc[1][nt] = __builtin_amdgcn_mfma_f32_16x16x32_f16(a1, bw2[ks][nt], acc[1][nt], 0, 0, 0);
    }
  }

  // Epilogue: bias + relu, write h2 f16 back into this wave's own a_lds rows.
  // C/D layout: col = nt*16 + l16, row = prow0 + tr*16 + quad*4 + r (m89-verified).
  #pragma unroll
  for (int nt = 0; nt < 8; ++nt) {
    const float bias = b2[nt*16 + l16];
    #pragma unroll
    for (int tr = 0; tr < 2; ++tr)
      #pragma unroll
      for (int r = 0; r < 4; ++r) {
        float v = fmaxf(acc[tr][nt][r] + bias, 0.0f);
        a_lds[prow0 + tr*16 + quad*4 + r][nt*16 + l16] = (f16)v;
      }
  }

  // ---- Phase 3: f = h2 @ W3 + b3 (W3 zero-padded to 128x16), MFMA ----
  floatx4 acc3[2];
  acc3[0] = (floatx4)(0.0f); acc3[1] = (floatx4)(0.0f);
  #pragma unroll
  for (int ks = 0; ks < 4; ++ks) {
    const half8 bf = ((const half8*)wsW3)[ks*64 + lane];
    const half8 a0 = *(const half8*)&a_lds[prow0 + l16][ks*32 + quad*8];
    const half8 a1 = *(const half8*)&a_lds[prow0 + 16 + l16][ks*32 + quad*8];
    acc3[0] = __builtin_amdgcn_mfma_f32_16x16x32_f16(a0, bf, acc3[0], 0, 0, 0);
    acc3[1] = __builtin_amdgcn_mfma_f32_16x16x32_f16(a1, bf, acc3[1], 0, 0, 0);
  }
  if (l16 < 4) {                    // only cols 0..3 are real outputs
    const float bc = b3[l16];
    #pragma unroll
    for (int tr = 0; tr < 2; ++tr)
      #pragma unroll
      for (int r = 0; r < 4; ++r)
        f_lds[prow0 + tr*16 + quad*4 + r][l16] = acc3[tr][r] + bc;
  }
  __syncthreads();   // rendering reads 64 rows spanning 2 waves

  // ---- Phase 4: volume rendering, one wave per ray, lane = sample ----
  // T_i = prod_{j<i}(1-alpha_j) = exp(-delta * sum_{j<i} sigma_j)  (exact identity:
  // 1-alpha = exp(-sigma*delta)); prefix-sum sigma across the 64 lanes.
  if (w < NRAY_PER_BLK) {
    const int ray = blockIdx.x * NRAY_PER_BLK + w;
    const float4 fv = *(const float4*)&f_lds[w*64 + lane][0];
    const float sigma = fv.w;
    const float alpha = 1.0f - __expf(-sigma * delta);
    float S = sigma;
    #pragma unroll
    for (int off = 1; off < 64; off <<= 1) {
      float u = __shfl_up(S, off);
      if (lane >= off) S += u;
    }
    const float T  = __expf(-delta * (S - sigma));   // exclusive prefix
    const float wt = alpha * T;
    float cr = wt * fv.x, cg = wt * fv.y, cb = wt * fv.z;
    #pragma unroll
    for (int off = 32; off > 0; off >>= 1) {
      cr += __shfl_down(cr, off);
      cg += __shfl_down(cg, off);
      cb += __shfl_down(cb, off);
    }
    if (lane == 0) {
      out[ray*3+0] = cr; out[ray*3+1] = cg; out[ray*3+2] = cb;
    }
  }
}

extern "C" void kernel_launch(void* const* d_in, const int* in_sizes, int n_in,
                              void* d_out, int out_size, void* d_ws, size_t ws_size,
                              hipStream_t stream) {
  const float* origins = (const float*)d_in[0];
  const float* dirs    = (const float*)d_in[1];
  const float* W1      = (const float*)d_in[2];
  const float* b1      = (const float*)d_in[3];
  const float* W2      = (const float*)d_in[4];
  const float* b2      = (const float*)d_in[5];
  const float* W3      = (const float*)d_in[6];
  const float* b3      = (const float*)d_in[7];
  // d_in[8..10] = near(2), far(6), num_samples(64): fixed, baked as constants.
  float* out = (float*)d_out;

  f16* wsW2 = (f16*)d_ws;         // 16384 f16 = 32 KB (B-frag order)
  f16* wsW3 = wsW2 + 16384;       // 2048 f16 = 4 KB (B-frag order, zero-padded)

  nerf_setup<<<36, 256, 0, stream>>>(W2, W3, wsW2, wsW3);
  nerf_main<<<16384 / NRAY_PER_BLK, 256, 0, stream>>>(
      origins, dirs, W1, b1, b2, b3, wsW2, wsW3, out);
}

// Round 3
// 119.800 us; speedup vs baseline: 1.0827x; 1.0827x over previous
//
#include <hip/hip_runtime.h>

// NeRF fused kernel for MI355X (gfx950) — round 3 (round 2 + compile fix).
// Key changes vs round 1 (which was VALU-bound: VALUBusy 64%, MfmaUtil 23%):
//  * h1 = relu(po + m*pd) with po=o@W1+b1, pd=d@W1 per ray: kills the
//    32-iteration fp32 phase-1 loop (~450 VALU instr/wave -> ~20).
//  * Phase 2 computes h2^T = W2^T @ h1^T (operands swapped): h1 B-frags are
//    built IN REGISTERS from po/pd via v_pk_fma_f16 (no h1 LDS round-trip),
//    W2 A-frags use the IDENTICAL ws bytes as round 1 (layout formula is the
//    same under m<->n rename; both A and B lane layouts HW-verified by round 1).
//  * h2^T D-layout gives each lane 4 consecutive h2-cols -> packed cvt + bias
//    + relu + 16 ds_write_b64 (vs 64 scalar ds_write_b16).
//  * Phase 3 / rendering unchanged (verified).
// Fix vs round 2: cvt_pkrtz returns __fp16-vector type; bit_cast to h2v.

typedef _Float16 f16;
typedef __attribute__((ext_vector_type(2))) _Float16 h2v;
typedef __attribute__((ext_vector_type(8))) _Float16 half8;
typedef __attribute__((ext_vector_type(4))) float floatx4;

#define H 128
#define NS 64
#define A_STRIDE 132   // 128+4 f16: rows 264 B apart (8B-aligned for b64 writes)

static __device__ __forceinline__ h2v pkrtz(float a, float b) {
  return __builtin_bit_cast(h2v, __builtin_amdgcn_cvt_pkrtz(a, b));
}

// ---------------------------------------------------------------------------
// Setup: W2 -> f16 frags (A-layout for h2^T = W2^T@h1^T: value(j) =
// W2[ks*32+quad*8+j][mt*16+l16] at frag (ks*8+mt)*64+lane — byte-identical to
// round 1's B-frag table). W3 -> B-frags zero-padded to 16 cols. b2 -> packed
// f16 pairs ordered so lane (quad) loads its epilogue bias with uint2 loads:
// b32 index = quad*16 + mt*2 + p covers cols mt*16+quad*4+{2p,2p+1}.
// ---------------------------------------------------------------------------
__global__ void nerf_setup(const float* __restrict__ W2, const float* __restrict__ W3,
                           const float* __restrict__ b2,
                           f16* __restrict__ wsW2, f16* __restrict__ wsW3,
                           f16* __restrict__ wsB2) {
  int t = blockIdx.x * blockDim.x + threadIdx.x;
  if (t < 8192) {                       // W2 frags
    int j2 = t & 3, lane = (t >> 2) & 63, mt = (t >> 8) & 7, ks = t >> 11;
    int k = ks * 32 + ((lane >> 4) * 8) + 2 * j2;
    int n = mt * 16 + (lane & 15);
    wsW2[2 * t]     = (f16)W2[k * H + n];
    wsW2[2 * t + 1] = (f16)W2[(k + 1) * H + n];
  } else if (t < 9216) {                // W3 frags (B-layout, padded)
    int u = t - 8192;
    int j2 = u & 3, lane = (u >> 2) & 63, ks = u >> 8;
    int k = ks * 32 + ((lane >> 4) * 8) + 2 * j2;
    int c = lane & 15;
    wsW3[2 * u]     = (c < 4) ? (f16)W3[k * 4 + c]       : (f16)0.0f;
    wsW3[2 * u + 1] = (c < 4) ? (f16)W3[(k + 1) * 4 + c] : (f16)0.0f;
  } else if (t < 9344) {                // b2 packed pairs
    int i = t - 9216;                   // f16 element 0..127
    int b32i = i >> 1, e = i & 1;
    int quad = b32i >> 4, rem = b32i & 15, mt = rem >> 1, p = rem & 1;
    wsB2[i] = (f16)b2[mt * 16 + quad * 4 + 2 * p + e];
  }
}

// ---------------------------------------------------------------------------
// Main: block = 2 rays = 128 point-rows, 4 waves; wave owns 32 rows end-to-end
// (no barrier until rendering).
// ---------------------------------------------------------------------------
__global__ __launch_bounds__(256, 3) void nerf_main(
    const float* __restrict__ origins, const float* __restrict__ dirs,
    const float* __restrict__ W1, const float* __restrict__ b1,
    const float* __restrict__ b3,
    const f16* __restrict__ wsW2, const f16* __restrict__ wsW3,
    const f16* __restrict__ wsB2,
    float* __restrict__ out)
{
  __shared__ __align__(16) f16   a_lds[128][A_STRIDE];  // h2 staging
  __shared__ __align__(16) f16   popd[4][2][H];         // per-wave po/pd strips
  __shared__ __align__(16) float f_lds[128][4];         // MLP outputs

  const int t = threadIdx.x;
  const int w = t >> 6, lane = t & 63, quad = lane >> 4, l16 = lane & 15;
  const int prow0 = w * 32;
  const float delta = 4.0f / NS;       // (far-near)/NS, near=2 far=6 baked

  // ---- po/pd: po[k] = o@W1[:,k] + b1[k], pd[k] = d@W1[:,k]; f16-packed ----
  {
    const int ray = blockIdx.x * 2 + (w >> 1);
    const float o0 = origins[ray*3], o1 = origins[ray*3+1], o2 = origins[ray*3+2];
    const float d0 = dirs[ray*3],    d1 = dirs[ray*3+1],    d2 = dirs[ray*3+2];
    const int k0 = lane * 2;
    const float2 wr0 = *(const float2*)&W1[0*H + k0];
    const float2 wr1 = *(const float2*)&W1[1*H + k0];
    const float2 wr2 = *(const float2*)&W1[2*H + k0];
    const float2 bb  = *(const float2*)&b1[k0];
    float poa = fmaf(o2, wr2.x, fmaf(o1, wr1.x, fmaf(o0, wr0.x, bb.x)));
    float pob = fmaf(o2, wr2.y, fmaf(o1, wr1.y, fmaf(o0, wr0.y, bb.y)));
    float pda = fmaf(d2, wr2.x, fmaf(d1, wr1.x, d0 * wr0.x));
    float pdb = fmaf(d2, wr2.y, fmaf(d1, wr1.y, d0 * wr0.y));
    h2v po2; po2[0] = (f16)poa; po2[1] = (f16)pob;   // round-to-nearest cvts
    h2v pd2; pd2[0] = (f16)pda; pd2[1] = (f16)pdb;
    *(h2v*)&popd[w][0][k0] = po2;
    *(h2v*)&popd[w][1][k0] = pd2;
  }

  // m splats per row-tile: m is an exact f16 (multiple of 1/16, <= 6)
  half8 m8[2];
  #pragma unroll
  for (int tr = 0; tr < 2; ++tr) {
    const int s = (w & 1) * 32 + tr * 16 + l16;
    const f16 m = (f16)(2.0f + (s + 0.5f) * delta);
    m8[tr] = (half8)m;
  }

  // ---- Phase 2: h2^T = W2^T @ h1^T, MFMA 16x16x32 ----
  floatx4 acc[8][2];
  #pragma unroll
  for (int mt = 0; mt < 8; ++mt) { acc[mt][0] = (floatx4)(0.0f); acc[mt][1] = (floatx4)(0.0f); }

  const half8* w2f = (const half8*)wsW2;
  const half8 z8 = (half8)(f16)0.0f;
  #pragma unroll
  for (int ks = 0; ks < 4; ++ks) {
    half8 aw[8];
    #pragma unroll
    for (int mt = 0; mt < 8; ++mt) aw[mt] = w2f[(ks*8 + mt)*64 + lane];
    const half8 po8 = *(const half8*)&popd[w][0][ks*32 + quad*8];
    const half8 pd8 = *(const half8*)&popd[w][1][ks*32 + quad*8];
    #pragma unroll
    for (int tr = 0; tr < 2; ++tr) {
      half8 hb = pd8 * m8[tr] + po8;                       // v_pk_fma_f16 x4
      hb = __builtin_elementwise_max(hb, z8);              // v_pk_max_f16 x4
      #pragma unroll
      for (int mt = 0; mt < 8; ++mt)
        acc[mt][tr] = __builtin_amdgcn_mfma_f32_16x16x32_f16(aw[mt], hb, acc[mt][tr], 0, 0, 0);
    }
  }

  // ---- Epilogue: bias+relu packed, b64 writes. Lane holds h2-cols
  // mt*16+quad*4+r at point-row prow0+tr*16+l16 (D of h2^T). ----
  h2v bpk[8][2];
  {
    const uint2* bp = (const uint2*)wsB2;
    #pragma unroll
    for (int mt = 0; mt < 8; ++mt) {
      union { uint2 u; h2v h[2]; } pk;
      pk.u = bp[quad * 8 + mt];
      bpk[mt][0] = pk.h[0]; bpk[mt][1] = pk.h[1];
    }
  }
  const h2v z2 = (h2v)(f16)0.0f;
  #pragma unroll
  for (int mt = 0; mt < 8; ++mt)
    #pragma unroll
    for (int tr = 0; tr < 2; ++tr) {
      h2v c0 = pkrtz(acc[mt][tr][0], acc[mt][tr][1]);
      h2v c1 = pkrtz(acc[mt][tr][2], acc[mt][tr][3]);
      c0 = __builtin_elementwise_max((h2v)(c0 + bpk[mt][0]), z2);
      c1 = __builtin_elementwise_max((h2v)(c1 + bpk[mt][1]), z2);
      union { h2v h[2]; uint2 u; } pk; pk.h[0] = c0; pk.h[1] = c1;
      *(uint2*)&a_lds[prow0 + tr*16 + l16][mt*16 + quad*4] = pk.u;  // ds_write_b64
    }

  // ---- Phase 3: f = h2 @ W3pad (A from LDS b128, verified path) ----
  floatx4 acc3[2];
  acc3[0] = (floatx4)(0.0f); acc3[1] = (floatx4)(0.0f);
  const half8* w3f = (const half8*)wsW3;
  half8 w3[4];
  #pragma unroll
  for (int ks = 0; ks < 4; ++ks) w3[ks] = w3f[ks*64 + lane];
  #pragma unroll
  for (int tr = 0; tr < 2; ++tr)
    #pragma unroll
    for (int ks = 0; ks < 4; ++ks) {
      const half8 a = *(const half8*)&a_lds[prow0 + tr*16 + l16][ks*32 + quad*8];
      acc3[tr] = __builtin_amdgcn_mfma_f32_16x16x32_f16(a, w3[ks], acc3[tr], 0, 0, 0);
    }
  if (l16 < 4) {
    const float bc = b3[l16];
    #pragma unroll
    for (int tr = 0; tr < 2; ++tr)
      #pragma unroll
      for (int r = 0; r < 4; ++r)
        f_lds[prow0 + tr*16 + quad*4 + r][l16] = acc3[tr][r] + bc;
  }
  __syncthreads();   // rendering spans 2 waves per ray

  // ---- Phase 4: volume rendering (unchanged, verified) ----
  if (w < 2) {
    const int ray = blockIdx.x * 2 + w;
    const float4 fv = *(const float4*)&f_lds[w*64 + lane][0];
    const float sigma = fv.w;
    const float alpha = 1.0f - __expf(-sigma * delta);
    float S = sigma;
    #pragma unroll
    for (int off = 1; off < 64; off <<= 1) {
      float u = __shfl_up(S, off);
      if (lane >= off) S += u;
    }
    const float T  = __expf(-delta * (S - sigma));
    const float wt = alpha * T;
    float cr = wt * fv.x, cg = wt * fv.y, cb = wt * fv.z;
    #pragma unroll
    for (int off = 32; off > 0; off >>= 1) {
      cr += __shfl_down(cr, off);
      cg += __shfl_down(cg, off);
      cb += __shfl_down(cb, off);
    }
    if (lane == 0) {
      out[ray*3+0] = cr; out[ray*3+1] = cg; out[ray*3+2] = cb;
    }
  }
}

extern "C" void kernel_launch(void* const* d_in, const int* in_sizes, int n_in,
                              void* d_out, int out_size, void* d_ws, size_t ws_size,
                              hipStream_t stream) {
  const float* origins = (const float*)d_in[0];
  const float* dirs    = (const float*)d_in[1];
  const float* W1      = (const float*)d_in[2];
  const float* b1      = (const float*)d_in[3];
  const float* W2      = (const float*)d_in[4];
  const float* b2      = (const float*)d_in[5];
  const float* W3      = (const float*)d_in[6];
  const float* b3      = (const float*)d_in[7];
  float* out = (float*)d_out;

  f16* wsW2 = (f16*)d_ws;          // 16384 f16 = 32 KB
  f16* wsW3 = wsW2 + 16384;        // 2048 f16  = 4 KB
  f16* wsB2 = wsW3 + 2048;         // 128 f16   = 256 B

  nerf_setup<<<37, 256, 0, stream>>>(W2, W3, b2, wsW2, wsW3, wsB2);
  nerf_main<<<16384 / 2, 256, 0, stream>>>(
      origins, dirs, W1, b1, b3, wsW2, wsW3, wsB2, out);
}

// Round 4
// 111.739 us; speedup vs baseline: 1.1608x; 1.0721x over previous
//
#include <hip/hip_runtime.h>

// NeRF fused kernel for MI355X (gfx950) — round 4.
// Round 3 post-mortem: VALUBusy 32%, MfmaUtil 26% -> latency/TLP-bound, both
// pipes idle. MFMA floor is ~19 us; we were at 61. Fix: 2x MFMA per wave.
//  * Block = 4 rays, wave = 1 full ray (64 points, 4 n-tiles): acc[8][4],
//    128 phase-2 MFMAs/wave; W2 frag loads amortized 2x (L2 traffic halved).
//  * ZERO barriers: wave owns its ray end-to-end incl. rendering.
//  * aw (W2 frags) double-buffered across ks steps for load/MFMA overlap.
//  * A_STRIDE 136 (272 B rows): every ds_read_b128 truly 16B-aligned
//    (round 3's 132 gave 8B-aligned odd rows -> split LDS reads).

typedef _Float16 f16;
typedef __attribute__((ext_vector_type(2))) _Float16 h2v;
typedef __attribute__((ext_vector_type(8))) _Float16 half8;
typedef __attribute__((ext_vector_type(4))) float floatx4;

#define H 128
#define NS 64
#define A_STRIDE 136   // f16; 272 B rows -> 16B-aligned, 2-way bank alias (free)

static __device__ __forceinline__ h2v pkrtz(float a, float b) {
  return __builtin_bit_cast(h2v, __builtin_amdgcn_cvt_pkrtz(a, b));
}

// ---------------------------------------------------------------------------
// Setup (unchanged, HW-verified): W2 -> f16 A-frags for h2^T = W2^T@h1^T;
// W3 -> B-frags zero-padded to 16 cols; b2 -> packed pairs for epilogue uint2.
// ---------------------------------------------------------------------------
__global__ void nerf_setup(const float* __restrict__ W2, const float* __restrict__ W3,
                           const float* __restrict__ b2,
                           f16* __restrict__ wsW2, f16* __restrict__ wsW3,
                           f16* __restrict__ wsB2) {
  int t = blockIdx.x * blockDim.x + threadIdx.x;
  if (t < 8192) {                       // W2 frags
    int j2 = t & 3, lane = (t >> 2) & 63, mt = (t >> 8) & 7, ks = t >> 11;
    int k = ks * 32 + ((lane >> 4) * 8) + 2 * j2;
    int n = mt * 16 + (lane & 15);
    wsW2[2 * t]     = (f16)W2[k * H + n];
    wsW2[2 * t + 1] = (f16)W2[(k + 1) * H + n];
  } else if (t < 9216) {                // W3 frags (B-layout, padded)
    int u = t - 8192;
    int j2 = u & 3, lane = (u >> 2) & 63, ks = u >> 8;
    int k = ks * 32 + ((lane >> 4) * 8) + 2 * j2;
    int c = lane & 15;
    wsW3[2 * u]     = (c < 4) ? (f16)W3[k * 4 + c]       : (f16)0.0f;
    wsW3[2 * u + 1] = (c < 4) ? (f16)W3[(k + 1) * 4 + c] : (f16)0.0f;
  } else if (t < 9344) {                // b2 packed pairs
    int i = t - 9216;
    int b32i = i >> 1, e = i & 1;
    int quad = b32i >> 4, rem = b32i & 15, mt = rem >> 1, p = rem & 1;
    wsB2[i] = (f16)b2[mt * 16 + quad * 4 + 2 * p + e];
  }
}

// ---------------------------------------------------------------------------
// Main: block = 4 rays = 4 waves; wave = 1 ray = 64 point-rows, no barriers.
// ---------------------------------------------------------------------------
__global__ __launch_bounds__(256, 2) void nerf_main(
    const float* __restrict__ origins, const float* __restrict__ dirs,
    const float* __restrict__ W1, const float* __restrict__ b1,
    const float* __restrict__ b3,
    const f16* __restrict__ wsW2, const f16* __restrict__ wsW3,
    const f16* __restrict__ wsB2,
    float* __restrict__ out)
{
  __shared__ __align__(16) f16   a_lds[256][A_STRIDE];  // h2 staging (69.6 KB)
  __shared__ __align__(16) f16   popd[4][2][H];         // per-wave po/pd strips
  __shared__ __align__(16) float f_lds[4][64][4];       // render transpose

  const int t = threadIdx.x;
  const int w = t >> 6, lane = t & 63, quad = lane >> 4, l16 = lane & 15;
  const int prow0 = w * 64;
  const float delta = 4.0f / NS;       // near=2, far=6 baked
  const int ray = blockIdx.x * 4 + w;

  // ---- po/pd: po[k] = o@W1[:,k]+b1[k], pd[k] = d@W1[:,k]; f16 to LDS ----
  {
    const float o0 = origins[ray*3], o1 = origins[ray*3+1], o2 = origins[ray*3+2];
    const float d0 = dirs[ray*3],    d1 = dirs[ray*3+1],    d2 = dirs[ray*3+2];
    const int k0 = lane * 2;
    const float2 wr0 = *(const float2*)&W1[0*H + k0];
    const float2 wr1 = *(const float2*)&W1[1*H + k0];
    const float2 wr2 = *(const float2*)&W1[2*H + k0];
    const float2 bb  = *(const float2*)&b1[k0];
    float poa = fmaf(o2, wr2.x, fmaf(o1, wr1.x, fmaf(o0, wr0.x, bb.x)));
    float pob = fmaf(o2, wr2.y, fmaf(o1, wr1.y, fmaf(o0, wr0.y, bb.y)));
    float pda = fmaf(d2, wr2.x, fmaf(d1, wr1.x, d0 * wr0.x));
    float pdb = fmaf(d2, wr2.y, fmaf(d1, wr1.y, d0 * wr0.y));
    h2v po2; po2[0] = (f16)poa; po2[1] = (f16)pob;
    h2v pd2; pd2[0] = (f16)pda; pd2[1] = (f16)pdb;
    *(h2v*)&popd[w][0][k0] = po2;
    *(h2v*)&popd[w][1][k0] = pd2;
  }

  // m splats per n-tile: sample s = tr*16 + l16; m exact in f16 (mult of 1/32)
  half8 m8[4];
  #pragma unroll
  for (int tr = 0; tr < 4; ++tr)
    m8[tr] = (half8)(f16)(2.0f + (tr*16 + l16 + 0.5f) * delta);

  // ---- Phase 2: h2^T = W2^T @ h1^T, 4 ks x 4 tr x 8 mt MFMAs ----
  floatx4 acc[8][4];
  #pragma unroll
  for (int mt = 0; mt < 8; ++mt)
    #pragma unroll
    for (int tr = 0; tr < 4; ++tr) acc[mt][tr] = (floatx4)(0.0f);

  const half8* w2f = (const half8*)wsW2;
  const half8 z8 = (half8)(f16)0.0f;
  half8 awA[8], awB[8];
  #pragma unroll
  for (int mt = 0; mt < 8; ++mt) awA[mt] = w2f[mt*64 + lane];  // ks=0 prefetch

  #pragma unroll
  for (int ks = 0; ks < 4; ++ks) {
    half8* cur = (ks & 1) ? awB : awA;
    half8* nxt = (ks & 1) ? awA : awB;
    if (ks < 3) {
      #pragma unroll
      for (int mt = 0; mt < 8; ++mt) nxt[mt] = w2f[((ks+1)*8 + mt)*64 + lane];
    }
    const half8 po8 = *(const half8*)&popd[w][0][ks*32 + quad*8];
    const half8 pd8 = *(const half8*)&popd[w][1][ks*32 + quad*8];
    #pragma unroll
    for (int tr = 0; tr < 4; ++tr) {
      half8 hb = pd8 * m8[tr] + po8;                 // v_pk_fma_f16 x4
      hb = __builtin_elementwise_max(hb, z8);        // v_pk_max_f16 x4
      #pragma unroll
      for (int mt = 0; mt < 8; ++mt)
        acc[mt][tr] = __builtin_amdgcn_mfma_f32_16x16x32_f16(cur[mt], hb, acc[mt][tr], 0, 0, 0);
    }
  }

  // ---- Epilogue: packed bias+relu+cvt, b64 LDS writes (D: col=point, row=h2col) ----
  h2v bpk[8][2];
  {
    const uint2* bp = (const uint2*)wsB2;
    #pragma unroll
    for (int mt = 0; mt < 8; ++mt) {
      union { uint2 u; h2v h[2]; } pk;
      pk.u = bp[quad * 8 + mt];
      bpk[mt][0] = pk.h[0]; bpk[mt][1] = pk.h[1];
    }
  }
  const h2v z2 = (h2v)(f16)0.0f;
  #pragma unroll
  for (int mt = 0; mt < 8; ++mt)
    #pragma unroll
    for (int tr = 0; tr < 4; ++tr) {
      h2v c0 = pkrtz(acc[mt][tr][0], acc[mt][tr][1]);
      h2v c1 = pkrtz(acc[mt][tr][2], acc[mt][tr][3]);
      c0 = __builtin_elementwise_max((h2v)(c0 + bpk[mt][0]), z2);
      c1 = __builtin_elementwise_max((h2v)(c1 + bpk[mt][1]), z2);
      union { h2v h[2]; uint2 u; } pk; pk.h[0] = c0; pk.h[1] = c1;
      *(uint2*)&a_lds[prow0 + tr*16 + l16][mt*16 + quad*4] = pk.u;  // ds_write_b64
    }

  // ---- Phase 3: f = h2 @ W3pad ----
  floatx4 acc3[4];
  #pragma unroll
  for (int tr = 0; tr < 4; ++tr) acc3[tr] = (floatx4)(0.0f);
  const half8* w3f = (const half8*)wsW3;
  half8 w3[4];
  #pragma unroll
  for (int ks = 0; ks < 4; ++ks) w3[ks] = w3f[ks*64 + lane];
  #pragma unroll
  for (int tr = 0; tr < 4; ++tr)
    #pragma unroll
    for (int ks = 0; ks < 4; ++ks) {
      const half8 a = *(const half8*)&a_lds[prow0 + tr*16 + l16][ks*32 + quad*8];
      acc3[tr] = __builtin_amdgcn_mfma_f32_16x16x32_f16(a, w3[ks], acc3[tr], 0, 0, 0);
    }
  if (l16 < 4) {
    const float bc = b3[l16];
    #pragma unroll
    for (int tr = 0; tr < 4; ++tr)
      #pragma unroll
      for (int r = 0; r < 4; ++r)
        f_lds[w][tr*16 + quad*4 + r][l16] = acc3[tr][r] + bc;
  }
  // No barrier: same wave wrote these rows.

  // ---- Phase 4: volume rendering, wave renders its own ray, lane = sample ----
  {
    const float4 fv = *(const float4*)&f_lds[w][lane][0];
    const float sigma = fv.w;
    const float alpha = 1.0f - __expf(-sigma * delta);
    float S = sigma;
    #pragma unroll
    for (int off = 1; off < 64; off <<= 1) {
      float u = __shfl_up(S, off);
      if (lane >= off) S += u;
    }
    const float T  = __expf(-delta * (S - sigma));   // exclusive prefix
    const float wt = alpha * T;
    float cr = wt * fv.x, cg = wt * fv.y, cb = wt * fv.z;
    #pragma unroll
    for (int off = 32; off > 0; off >>= 1) {
      cr += __shfl_down(cr, off);
      cg += __shfl_down(cg, off);
      cb += __shfl_down(cb, off);
    }
    if (lane == 0) {
      out[ray*3+0] = cr; out[ray*3+1] = cg; out[ray*3+2] = cb;
    }
  }
}

extern "C" void kernel_launch(void* const* d_in, const int* in_sizes, int n_in,
                              void* d_out, int out_size, void* d_ws, size_t ws_size,
                              hipStream_t stream) {
  const float* origins = (const float*)d_in[0];
  const float* dirs    = (const float*)d_in[1];
  const float* W1      = (const float*)d_in[2];
  const float* b1      = (const float*)d_in[3];
  const float* W2      = (const float*)d_in[4];
  const float* b2      = (const float*)d_in[5];
  const float* W3      = (const float*)d_in[6];
  const float* b3      = (const float*)d_in[7];
  float* out = (float*)d_out;

  f16* wsW2 = (f16*)d_ws;          // 16384 f16 = 32 KB
  f16* wsW3 = wsW2 + 16384;        // 2048 f16  = 4 KB
  f16* wsB2 = wsW3 + 2048;         // 128 f16   = 256 B

  nerf_setup<<<37, 256, 0, stream>>>(W2, W3, b2, wsW2, wsW3, wsB2);
  nerf_main<<<16384 / 4, 256, 0, stream>>>(
      origins, dirs, W1, b1, b3, wsW2, wsW3, wsB2, out);
}